// Round 1
// baseline (1218.172 us; speedup 1.0000x reference)
//
#include <hip/hip_runtime.h>
#include <math.h>

#define DEV __device__ __forceinline__

constexpr int B = 4, L = 200, SP = 225;
constexpr int C1 = 4, D1 = 200;
constexpr int C2N = 8, D2 = 100;
constexpr int C3N = 4, D3 = 50;
constexpr int D4 = 25;
constexpr float EPS = 1e-5f;

// ---- workspace layout (float offsets) ----
constexpr size_t OFF_IMG = 0;                      // B*L*SP
constexpr size_t OFF_F1  = OFF_IMG + 180000;       // B*C1*D1*SP
constexpr size_t OFF_E2  = OFF_F1  + 720000;
constexpr size_t OFF_E1  = OFF_E2  + 720000;
constexpr size_t OFF_SS1 = OFF_E1  + 720000;       // 6*3200
constexpr size_t OFF_PAR = OFF_SS1 + 19200;        // 1024 params
constexpr size_t OFF_F2  = OFF_PAR + 1024;         // B*C2N*D2*SP
constexpr size_t OFF_C2  = OFF_F2  + 720000;       // C2N*SP
constexpr size_t OFF_T2  = OFF_C2  + 1800;         // B*L*2*C2N*SP
constexpr size_t OFF_SS2F= OFF_T2  + 2880000;      // 2*3200
constexpr size_t OFF_SS2T= OFF_SS2F+ 6400;         // 2*25600
constexpr size_t OFF_SS2C= OFF_SS2T+ 51200;        // 16
constexpr size_t OFF_F3  = OFF_SS2C+ 16;           // B*C3N*D3*SP
constexpr size_t OFF_C3  = OFF_F3  + 180000;       // C3N*SP
constexpr size_t OFF_T3  = OFF_C3  + 900;          // B*L*2*C3N*SP
constexpr size_t OFF_SS3F= OFF_T3  + 1440000;      // 2*800
constexpr size_t OFF_SS3T= OFF_SS3F+ 1600;         // 2*6400
constexpr size_t OFF_SS3C= OFF_SS3T+ 12800;        // 8
constexpr size_t OFF_F4  = OFF_SS3C+ 8;            // B*D4*SP
constexpr size_t OFF_C4  = OFF_F4  + 22500;        // SP
constexpr size_t OFF_T4  = OFF_C4  + 225;          // B*L*2*SP
constexpr size_t OFF_SS4F= OFF_T4  + 360000;       // 2*100
constexpr size_t OFF_SS4T= OFF_SS4F+ 200;          // 2*1600
constexpr size_t OFF_SS4C= OFF_SS4T+ 3200;         // 2
constexpr size_t OFF_Z   = OFF_SS4C+ 2;            // B*L*25*SP
constexpr size_t OFF_CB  = OFF_Z   + 4500000;
constexpr size_t OFF_P2D = OFF_CB  + 4500000;      // 800*25*2
constexpr size_t WS_FLOATS = OFF_P2D + 40000;

// params layout: 0..3 scale1, 4..7 shift1, 8..11 Z1, 16..23 scale2, 24..31 shift2,
// 32..35 scale3, 36..39 shift3, 40 scale4, 41 shift4, 48..72 scale2d, 80..104 shift2d

DEV float blockSum(float v, float* red) {
    int tid = threadIdx.x;
    red[tid] = v; __syncthreads();
    for (int s = 128; s > 0; s >>= 1) { if (tid < s) red[tid] += red[tid + s]; __syncthreads(); }
    float r = red[0]; __syncthreads(); return r;
}
DEV double blockSumD(double v, double* red) {
    int tid = threadIdx.x;
    red[tid] = v; __syncthreads();
    for (int s = 128; s > 0; s >>= 1) { if (tid < s) red[tid] += red[tid + s]; __syncthreads(); }
    double r = red[0]; __syncthreads(); return r;
}
// 3x3 spatial conv of one 15x15 plane at (y,x), zero pad
DEV float conv9(const float* S, const float* w, int y, int x) {
    float a = 0.f;
    for (int ky = 0; ky < 3; ky++) { int yy = y + ky - 1; if (yy < 0 || yy >= 15) continue;
        for (int kx = 0; kx < 3; kx++) { int xx = x + kx - 1; if (xx < 0 || xx >= 15) continue;
            a += w[ky * 3 + kx] * S[yy * 15 + xx]; } }
    return a;
}
DEV float wsum9(const float* w, int y, int x) {
    float a = 0.f;
    for (int ky = 0; ky < 3; ky++) { int yy = y + ky - 1; if (yy < 0 || yy >= 15) continue;
        for (int kx = 0; kx < 3; kx++) { int xx = x + kx - 1; if (xx < 0 || xx >= 15) continue;
            a += w[ky * 3 + kx]; } }
    return a;
}

// ---------------- embedding ----------------
__global__ void k_embed(const int* __restrict__ xi, const float* __restrict__ emb, float* __restrict__ img) {
    int idx = blockIdx.x * 256 + threadIdx.x;
    if (idx >= B * L * SP) return;
    int p = idx % SP; int bl = idx / SP;
    img[idx] = emb[(size_t)xi[bl] * SP + p];
}

// ---------------- layer 1: F1/E2/E1 streams + slice sums ----------------
__global__ __launch_bounds__(256) void k_layer1(const float* __restrict__ img, const float* __restrict__ w3a,
                        float* F1, float* E2, float* E1, float* SS1) {
    __shared__ float wl[27];
    __shared__ float red[256];
    int blk = blockIdx.x;
    int d = blk % D1; int c = (blk / D1) % C1; int b = blk / (D1 * C1);
    int tid = threadIdx.x;
    if (tid < 27) wl[tid] = w3a[c * 27 + tid];
    __syncthreads();
    float f1 = 0.f, e2 = 0.f, e1 = 0.f;
    int y = tid / 15, x = tid % 15;
    if (tid < 225) {
        float P[3];
        for (int t = 0; t < 3; t++) {
            int j = d + t - 1; float acc = 0.f;
            if (j >= 0 && j < L) acc = conv9(img + ((size_t)b * L + j) * SP, wl + t * 9, y, x);
            P[t] = acc;
        }
        f1 = P[0] + P[1] + P[2]; e2 = P[0] + P[1]; e1 = (d >= 1) ? P[0] : 0.f;
        size_t o = ((size_t)(b * C1 + c) * D1 + d) * SP + tid;
        F1[o] = f1; E2[o] = e2; E1[o] = e1;
    }
    int slice = (b * C1 + c) * D1 + d;
    float sF = blockSum(tid < 225 ? f1 : 0.f, red);
    float qF = blockSum(tid < 225 ? f1 * f1 : 0.f, red);
    float sE2 = blockSum(tid < 225 ? e2 : 0.f, red);
    float qE2 = blockSum(tid < 225 ? e2 * e2 : 0.f, red);
    float sE1 = blockSum(tid < 225 ? e1 : 0.f, red);
    float qE1 = blockSum(tid < 225 ? e1 * e1 : 0.f, red);
    if (tid == 0) {
        SS1[slice] = sF; SS1[3200 + slice] = qF;
        SS1[6400 + slice] = sE2; SS1[9600 + slice] = qE2;
        SS1[12800 + slice] = sE1; SS1[16000 + slice] = qE1;
    }
}

__global__ void k_stats1(const float* SS1, const float* g, const float* bb, float* par) {
    __shared__ double dred[256];
    int c = blockIdx.x; int tid = threadIdx.x;
    double s = 0, q = 0;
    for (int idx = tid; idx < B * D1; idx += 256) {
        int b = idx / D1, d = idx % D1;
        int sl = (b * C1 + c) * D1 + d;
        double wF = (double)(L - 1 - d);
        s += wF * SS1[sl] + SS1[6400 + sl] + (d >= 1 ? SS1[12800 + sl] : 0.0);
        q += wF * SS1[3200 + sl] + SS1[9600 + sl] + (d >= 1 ? SS1[16000 + sl] : 0.0);
    }
    s = blockSumD(s, dred); q = blockSumD(q, dred);
    if (tid == 0) {
        double N = (double)B * L * D1 * SP;
        double mean = s / N, var = q / N - mean * mean;
        float sc = g[c] / (float)sqrt(var + (double)EPS);
        float sh = bb[c] - (float)mean * sc;
        par[c] = sc; par[4 + c] = sh; par[8 + c] = fmaxf(sh, 0.f);
    }
}

__global__ void k_apply1(float* base, const float* par) {
    int idx = blockIdx.x * 256 + threadIdx.x;
    if (idx >= 3 * 720000) return;
    int r = idx % 720000;
    int c = (r / 45000) % C1;
    base[idx] = fmaxf(par[c] * base[idx] + par[4 + c], 0.f);
}

// ---------------- layer 2 ----------------
__global__ __launch_bounds__(256) void k_F2(const float* FH1, const float* __restrict__ w3b, float* F2, float* SS2F) {
    __shared__ float wl[108]; __shared__ float red[256];
    int blk = blockIdx.x; int d2 = blk % D2; int c2 = (blk / D2) % C2N; int b = blk / (D2 * C2N);
    int tid = threadIdx.x;
    if (tid < 108) wl[tid] = w3b[c2 * 108 + tid];
    __syncthreads();
    float acc = 0.f; int y = tid / 15, x = tid % 15;
    if (tid < 225) {
        for (int t = 0; t < 3; t++) {
            int j = 2 * d2 - 1 + t; if (j < 0 || j >= D1) continue;
            for (int c = 0; c < C1; c++)
                acc += conv9(FH1 + ((size_t)(b * C1 + c) * D1 + j) * SP, wl + c * 27 + t * 9, y, x);
        }
        F2[(size_t)blk * SP + tid] = acc;
    }
    float sm = blockSum(tid < 225 ? acc : 0.f, red);
    float sq = blockSum(tid < 225 ? acc * acc : 0.f, red);
    if (tid == 0) { SS2F[blk] = sm; SS2F[3200 + blk] = sq; }
}

__global__ void k_C2(const float* par, const float* __restrict__ w3b, float* C2b, float* SS2C) {
    __shared__ float red[256];
    int tid = threadIdx.x; int y = tid / 15, x = tid % 15;
    for (int c2 = 0; c2 < C2N; c2++) {
        float acc = 0.f;
        if (tid < 225) {
            for (int c = 0; c < C1; c++) {
                float z1 = par[8 + c];
                for (int t = 0; t < 3; t++)
                    acc += z1 * wsum9(w3b + c2 * 108 + c * 27 + t * 9, y, x);
            }
            C2b[c2 * SP + tid] = acc;
        }
        float sm = blockSum(tid < 225 ? acc : 0.f, red);
        float sq = blockSum(tid < 225 ? acc * acc : 0.f, red);
        if (tid == 0) { SS2C[c2 * 2] = sm; SS2C[c2 * 2 + 1] = sq; }
    }
}

__global__ __launch_bounds__(256) void k_T2(const float* FH1, const float* EH2, const float* EH1, const float* par,
                    const float* __restrict__ w3b, float* T2, float* SS2T) {
    __shared__ float wl[864]; __shared__ float red[256];
    int blk = blockIdx.x; int i = blk % L, b = blk / L; int tid = threadIdx.x;
    int t2a = i >> 1;
    for (int k = tid; k < 864; k += 256) wl[k] = w3b[k];
    __syncthreads();
    int y = tid / 15, x = tid % 15;
    for (int k = 0; k < 2; k++) {
        int d2 = t2a + k;
        float vals[C2N];
        for (int c2 = 0; c2 < C2N; c2++) vals[c2] = 0.f;
        if (d2 < D2 && tid < 225) {
            for (int t = 0; t < 3; t++) {
                int j = 2 * d2 - 1 + t; if (j < 0 || j >= D1) continue;
                int cat = (j <= i - 1) ? 0 : ((j == i) ? 1 : ((j == i + 1) ? 2 : 3));
                for (int c = 0; c < C1; c++) {
                    if (cat == 3) {
                        float z1 = par[8 + c];
                        for (int c2 = 0; c2 < C2N; c2++)
                            vals[c2] += z1 * wsum9(wl + c2 * 108 + c * 27 + t * 9, y, x);
                    } else {
                        const float* S = (cat == 0 ? FH1 : (cat == 1 ? EH2 : EH1)) + ((size_t)(b * C1 + c) * D1 + j) * SP;
                        for (int c2 = 0; c2 < C2N; c2++)
                            vals[c2] += conv9(S, wl + c2 * 108 + c * 27 + t * 9, y, x);
                    }
                }
            }
        }
        for (int c2 = 0; c2 < C2N; c2++) {
            if (tid < 225) T2[(((size_t)blk * 2 + k) * C2N + c2) * SP + tid] = vals[c2];
            float sm = blockSum(tid < 225 ? vals[c2] : 0.f, red);
            float sq = blockSum(tid < 225 ? vals[c2] * vals[c2] : 0.f, red);
            if (tid == 0) { int sl = (blk * 2 + k) * C2N + c2; SS2T[sl] = sm; SS2T[25600 + sl] = sq; }
        }
    }
}

__global__ void k_stats2(const float* SS2F, const float* SS2T, const float* SS2C,
                         const float* g, const float* bb, float* par) {
    __shared__ double dred[256];
    int c2 = blockIdx.x; int tid = threadIdx.x;
    double s = 0, q = 0;
    for (int idx = tid; idx < B * L * D2; idx += 256) {
        int d2 = idx % D2; int i = (idx / D2) % L; int b = idx / (D2 * L);
        int t2a = i >> 1;
        if (d2 < t2a) { int sl = (b * C2N + c2) * D2 + d2; s += SS2F[sl]; q += SS2F[3200 + sl]; }
        else if (d2 <= t2a + 1) { int k = d2 - t2a; int sl = ((b * L + i) * 2 + k) * C2N + c2; s += SS2T[sl]; q += SS2T[25600 + sl]; }
        else { s += SS2C[c2 * 2]; q += SS2C[c2 * 2 + 1]; }
    }
    s = blockSumD(s, dred); q = blockSumD(q, dred);
    if (tid == 0) {
        double N = (double)B * L * D2 * SP;
        double mean = s / N, var = q / N - mean * mean;
        float sc = g[c2] / (float)sqrt(var + (double)EPS);
        float sh = bb[c2] - (float)mean * sc;
        par[16 + c2] = sc; par[24 + c2] = sh;
    }
}

__global__ void k_apply2(float* base, const float* par) {
    int idx = blockIdx.x * 256 + threadIdx.x;
    if (idx >= 3601800) return;
    int c2;
    if (idx < 720000) c2 = (idx / 22500) % C2N;
    else if (idx < 721800) c2 = (idx - 720000) / SP;
    else c2 = ((idx - 721800) / SP) % C2N;
    base[idx] = fmaxf(par[16 + c2] * base[idx] + par[24 + c2], 0.f);
}

// ---------------- layer 3 ----------------
__global__ __launch_bounds__(256) void k_F3(const float* FH2, const float* __restrict__ w3c, float* F3, float* SS3F) {
    __shared__ float wl[216]; __shared__ float red[256];
    int blk = blockIdx.x; int d3 = blk % D3; int c3 = (blk / D3) % C3N; int b = blk / (D3 * C3N);
    int tid = threadIdx.x;
    if (tid < 216) wl[tid] = w3c[c3 * 216 + tid];
    __syncthreads();
    float acc = 0.f; int y = tid / 15, x = tid % 15;
    if (tid < 225) {
        for (int t = 0; t < 3; t++) {
            int j2 = 2 * d3 - 1 + t; if (j2 < 0 || j2 >= D2) continue;
            for (int c2 = 0; c2 < C2N; c2++)
                acc += conv9(FH2 + ((size_t)(b * C2N + c2) * D2 + j2) * SP, wl + c2 * 27 + t * 9, y, x);
        }
        F3[(size_t)blk * SP + tid] = acc;
    }
    float sm = blockSum(tid < 225 ? acc : 0.f, red);
    float sq = blockSum(tid < 225 ? acc * acc : 0.f, red);
    if (tid == 0) { SS3F[blk] = sm; SS3F[800 + blk] = sq; }
}

__global__ void k_C3(const float* ZH2, const float* __restrict__ w3c, float* C3b, float* SS3C) {
    __shared__ float red[256];
    int tid = threadIdx.x; int y = tid / 15, x = tid % 15;
    for (int c3 = 0; c3 < C3N; c3++) {
        float acc = 0.f;
        if (tid < 225) {
            for (int t = 0; t < 3; t++)
                for (int c2 = 0; c2 < C2N; c2++)
                    acc += conv9(ZH2 + c2 * SP, w3c + c3 * 216 + c2 * 27 + t * 9, y, x);
            C3b[c3 * SP + tid] = acc;
        }
        float sm = blockSum(tid < 225 ? acc : 0.f, red);
        float sq = blockSum(tid < 225 ? acc * acc : 0.f, red);
        if (tid == 0) { SS3C[c3 * 2] = sm; SS3C[c3 * 2 + 1] = sq; }
    }
}

__global__ __launch_bounds__(256) void k_T3(const float* FH2, const float* TH2, const float* ZH2,
                    const float* __restrict__ w3c, float* T3, float* SS3T) {
    __shared__ float wl[864]; __shared__ float red[256];
    int blk = blockIdx.x; int i = blk % L, b = blk / L; int tid = threadIdx.x;
    int t2a = i >> 1, t3a = i >> 2;
    for (int k = tid; k < 864; k += 256) wl[k] = w3c[k];
    __syncthreads();
    int y = tid / 15, x = tid % 15;
    for (int k = 0; k < 2; k++) {
        int d3 = t3a + k;
        float vals[C3N] = {0.f, 0.f, 0.f, 0.f};
        if (d3 < D3 && tid < 225) {
            for (int t = 0; t < 3; t++) {
                int j2 = 2 * d3 - 1 + t; if (j2 < 0 || j2 >= D2) continue;
                for (int c2 = 0; c2 < C2N; c2++) {
                    const float* S;
                    if (j2 < t2a) S = FH2 + ((size_t)(b * C2N + c2) * D2 + j2) * SP;
                    else if (j2 == t2a) S = TH2 + (((size_t)blk * 2 + 0) * C2N + c2) * SP;
                    else if (j2 == t2a + 1) S = TH2 + (((size_t)blk * 2 + 1) * C2N + c2) * SP;
                    else S = ZH2 + c2 * SP;
                    for (int c3 = 0; c3 < C3N; c3++)
                        vals[c3] += conv9(S, wl + c3 * 216 + c2 * 27 + t * 9, y, x);
                }
            }
        }
        for (int c3 = 0; c3 < C3N; c3++) {
            if (tid < 225) T3[(((size_t)blk * 2 + k) * C3N + c3) * SP + tid] = vals[c3];
            float sm = blockSum(tid < 225 ? vals[c3] : 0.f, red);
            float sq = blockSum(tid < 225 ? vals[c3] * vals[c3] : 0.f, red);
            if (tid == 0) { int sl = (blk * 2 + k) * C3N + c3; SS3T[sl] = sm; SS3T[6400 + sl] = sq; }
        }
    }
}

__global__ void k_stats3(const float* SS3F, const float* SS3T, const float* SS3C,
                         const float* g, const float* bb, float* par) {
    __shared__ double dred[256];
    int c3 = blockIdx.x; int tid = threadIdx.x;
    double s = 0, q = 0;
    for (int idx = tid; idx < B * L * D3; idx += 256) {
        int d3 = idx % D3; int i = (idx / D3) % L; int b = idx / (D3 * L);
        int t3a = i >> 2;
        if (d3 < t3a) { int sl = (b * C3N + c3) * D3 + d3; s += SS3F[sl]; q += SS3F[800 + sl]; }
        else if (d3 <= t3a + 1) { int k = d3 - t3a; int sl = ((b * L + i) * 2 + k) * C3N + c3; s += SS3T[sl]; q += SS3T[6400 + sl]; }
        else { s += SS3C[c3 * 2]; q += SS3C[c3 * 2 + 1]; }
    }
    s = blockSumD(s, dred); q = blockSumD(q, dred);
    if (tid == 0) {
        double N = (double)B * L * D3 * SP;
        double mean = s / N, var = q / N - mean * mean;
        float sc = g[c3] / (float)sqrt(var + (double)EPS);
        float sh = bb[c3] - (float)mean * sc;
        par[32 + c3] = sc; par[36 + c3] = sh;
    }
}

__global__ void k_apply3(float* base, const float* par) {
    int idx = blockIdx.x * 256 + threadIdx.x;
    if (idx >= 1620900) return;
    int c3;
    if (idx < 180000) c3 = (idx / 11250) % C3N;
    else if (idx < 180900) c3 = (idx - 180000) / SP;
    else c3 = ((idx - 180900) / SP) % C3N;
    base[idx] = fmaxf(par[32 + c3] * base[idx] + par[36 + c3], 0.f);
}

// ---------------- layer 4 ----------------
__global__ __launch_bounds__(256) void k_F4(const float* FH3, const float* __restrict__ w3d, float* F4, float* SS4F) {
    __shared__ float wl[108]; __shared__ float red[256];
    int blk = blockIdx.x; int d4 = blk % D4; int b = blk / D4; int tid = threadIdx.x;
    if (tid < 108) wl[tid] = w3d[tid];
    __syncthreads();
    float acc = 0.f; int y = tid / 15, x = tid % 15;
    if (tid < 225) {
        for (int t = 0; t < 3; t++) {
            int j3 = 2 * d4 - 1 + t; if (j3 < 0 || j3 >= D3) continue;
            for (int c3 = 0; c3 < C3N; c3++)
                acc += conv9(FH3 + ((size_t)(b * C3N + c3) * D3 + j3) * SP, wl + c3 * 27 + t * 9, y, x);
        }
        F4[(size_t)blk * SP + tid] = acc;
    }
    float sm = blockSum(tid < 225 ? acc : 0.f, red);
    float sq = blockSum(tid < 225 ? acc * acc : 0.f, red);
    if (tid == 0) { SS4F[blk] = sm; SS4F[100 + blk] = sq; }
}

__global__ void k_C4(const float* ZH3, const float* __restrict__ w3d, float* C4b, float* SS4C) {
    __shared__ float red[256];
    int tid = threadIdx.x; int y = tid / 15, x = tid % 15;
    float acc = 0.f;
    if (tid < 225) {
        for (int t = 0; t < 3; t++)
            for (int c3 = 0; c3 < C3N; c3++)
                acc += conv9(ZH3 + c3 * SP, w3d + c3 * 27 + t * 9, y, x);
        C4b[tid] = acc;
    }
    float sm = blockSum(tid < 225 ? acc : 0.f, red);
    float sq = blockSum(tid < 225 ? acc * acc : 0.f, red);
    if (tid == 0) { SS4C[0] = sm; SS4C[1] = sq; }
}

__global__ __launch_bounds__(256) void k_T4(const float* FH3, const float* TH3, const float* ZH3,
                    const float* __restrict__ w3d, float* T4, float* SS4T) {
    __shared__ float wl[108]; __shared__ float red[256];
    int blk = blockIdx.x; int i = blk % L, b = blk / L; int tid = threadIdx.x;
    int t3a = i >> 2, t4a = i >> 3;
    if (tid < 108) wl[tid] = w3d[tid];
    __syncthreads();
    int y = tid / 15, x = tid % 15;
    for (int k = 0; k < 2; k++) {
        int d4 = t4a + k; float acc = 0.f;
        if (d4 < D4 && tid < 225) {
            for (int t = 0; t < 3; t++) {
                int j3 = 2 * d4 - 1 + t; if (j3 < 0 || j3 >= D3) continue;
                for (int c3 = 0; c3 < C3N; c3++) {
                    const float* S;
                    if (j3 < t3a) S = FH3 + ((size_t)(b * C3N + c3) * D3 + j3) * SP;
                    else if (j3 == t3a) S = TH3 + (((size_t)blk * 2 + 0) * C3N + c3) * SP;
                    else if (j3 == t3a + 1) S = TH3 + (((size_t)blk * 2 + 1) * C3N + c3) * SP;
                    else S = ZH3 + c3 * SP;
                    acc += conv9(S, wl + c3 * 27 + t * 9, y, x);
                }
            }
        }
        if (tid < 225) T4[((size_t)blk * 2 + k) * SP + tid] = acc;
        float sm = blockSum(tid < 225 ? acc : 0.f, red);
        float sq = blockSum(tid < 225 ? acc * acc : 0.f, red);
        if (tid == 0) { SS4T[blk * 2 + k] = sm; SS4T[1600 + blk * 2 + k] = sq; }
    }
}

__global__ void k_stats4(const float* SS4F, const float* SS4T, const float* SS4C,
                         const float* g, const float* bb, float* par) {
    __shared__ double dred[256];
    int tid = threadIdx.x; double s = 0, q = 0;
    for (int idx = tid; idx < B * L * D4; idx += 256) {
        int d4 = idx % D4; int i = (idx / D4) % L; int b = idx / (D4 * L);
        int t4a = i >> 3;
        if (d4 < t4a) { s += SS4F[b * D4 + d4]; q += SS4F[100 + b * D4 + d4]; }
        else if (d4 <= t4a + 1) { int k = d4 - t4a; s += SS4T[(b * L + i) * 2 + k]; q += SS4T[1600 + (b * L + i) * 2 + k]; }
        else { s += SS4C[0]; q += SS4C[1]; }
    }
    s = blockSumD(s, dred); q = blockSumD(q, dred);
    if (tid == 0) {
        double N = (double)B * L * D4 * SP;
        double mean = s / N, var = q / N - mean * mean;
        float sc = g[0] / (float)sqrt(var + (double)EPS);
        float sh = bb[0] - (float)mean * sc;
        par[40] = sc; par[41] = sh;
    }
}

__global__ void k_apply4(float* base, const float* par) {
    int idx = blockIdx.x * 256 + threadIdx.x;
    if (idx >= 382725) return;
    base[idx] = fmaxf(par[40] * base[idx] + par[41], 0.f);
}

// ---------------- build z ----------------
__global__ void k_buildz(const float* FH4, const float* TH4, const float* ZH4, float* z) {
    int s = blockIdx.x, tid = threadIdx.x;
    int i = s % L, b = s / L; int t4a = i >> 3;
    for (int e = tid; e < D4 * SP; e += 256) {
        int d4 = e / SP, p = e % SP; float v;
        if (d4 < t4a) v = FH4[((size_t)b * D4 + d4) * SP + p];
        else if (d4 == t4a) v = TH4[((size_t)s * 2 + 0) * SP + p];
        else if (d4 == t4a + 1) v = TH4[((size_t)s * 2 + 1) * SP + p];
        else v = ZH4[p];
        z[(size_t)s * D4 * SP + e] = v;
    }
}

// ---------------- 2D residual conv loop ----------------
__global__ __launch_bounds__(256) void k_conv2d(const float* __restrict__ z, const float* __restrict__ w2it,
                        float* __restrict__ cbuf, float* __restrict__ part) {
    __shared__ float zs[5625];
    __shared__ float wl[5625];
    __shared__ float rowsum[375], rowsq[375];
    int s = blockIdx.x, tid = threadIdx.x;
    for (int k = tid; k < 5625; k += 256) { zs[k] = z[(size_t)s * 5625 + k]; wl[k] = w2it[k]; }
    __syncthreads();
    for (int r = tid; r < 375; r += 256) {
        int c2 = r / 15, y = r % 15;
        float acc[15];
        #pragma unroll
        for (int xx = 0; xx < 15; xx++) acc[xx] = 0.f;
        const float* wrow = wl + c2 * 225;
        for (int c = 0; c < 25; c++) {
            const float* wcc = wrow + c * 9;
            for (int ky = 0; ky < 3; ky++) {
                int yy = y + ky - 1; if (yy < 0 || yy >= 15) continue;
                const float* zr = zs + c * 225 + yy * 15;
                float w0 = wcc[ky * 3 + 0], w1 = wcc[ky * 3 + 1], w2v = wcc[ky * 3 + 2];
                acc[0] += w1 * zr[0] + w2v * zr[1];
                #pragma unroll
                for (int xx = 1; xx < 14; xx++) acc[xx] += w0 * zr[xx - 1] + w1 * zr[xx] + w2v * zr[xx + 1];
                acc[14] += w0 * zr[13] + w1 * zr[14];
            }
        }
        float sm = 0.f, sq = 0.f;
        #pragma unroll
        for (int xx = 0; xx < 15; xx++) {
            float v = acc[xx]; sm += v; sq += v * v;
            cbuf[(size_t)s * 5625 + r * 15 + xx] = v;
        }
        rowsum[r] = sm; rowsq[r] = sq;
    }
    __syncthreads();
    if (tid < 25) {
        float sm = 0.f, sq = 0.f;
        for (int r = tid * 15; r < tid * 15 + 15; r++) { sm += rowsum[r]; sq += rowsq[r]; }
        part[((size_t)s * 25 + tid) * 2] = sm; part[((size_t)s * 25 + tid) * 2 + 1] = sq;
    }
}

__global__ void k_stats2d(const float* part, const float* g, const float* bb, float* par) {
    __shared__ double dred[256];
    int c = blockIdx.x, tid = threadIdx.x;
    double s = 0, q = 0;
    for (int ss = tid; ss < B * L; ss += 256) { s += part[((size_t)ss * 25 + c) * 2]; q += part[((size_t)ss * 25 + c) * 2 + 1]; }
    s = blockSumD(s, dred); q = blockSumD(q, dred);
    if (tid == 0) {
        double N = (double)B * L * SP;
        double mean = s / N, var = q / N - mean * mean;
        float sc = g[c] / (float)sqrt(var + (double)EPS);
        float sh = bb[c] - (float)mean * sc;
        par[48 + c] = sc; par[80 + c] = sh;
    }
}

__global__ void k_apply2d(float* z, const float* cbuf, const float* par) {
    int idx = blockIdx.x * 256 + threadIdx.x;
    if (idx >= B * L * 25 * SP) return;
    int c = (idx / SP) % 25;
    z[idx] += fmaxf(par[48 + c] * cbuf[idx] + par[80 + c], 0.f);
}

// ---------------- head: pool + concat + fc1(tanh) + fc2(sigmoid) ----------------
__global__ __launch_bounds__(256) void k_head(const float* __restrict__ z, const float* __restrict__ img,
                      const float* __restrict__ fc1w, const float* __restrict__ fc1b,
                      const float* __restrict__ fc2w, const float* __restrict__ fc2b,
                      float* __restrict__ out) {
    __shared__ float feat[450];
    __shared__ float hfc[256];
    int s = blockIdx.x, tid = threadIdx.x;
    if (tid < 225) {
        float sm = 0.f;
        for (int c = 0; c < 25; c++) sm += z[(size_t)s * 5625 + c * 225 + tid];
        feat[tid] = sm * (1.f / 25.f);
        feat[225 + tid] = img[(size_t)s * 225 + tid];
    }
    __syncthreads();
    float h = 0.f;
    if (tid < 200) {
        float acc = fc1b[tid];
        const float* wr = fc1w + (size_t)tid * 450;
        for (int k = 0; k < 450; k++) acc += feat[k] * wr[k];
        h = tanhf(acc);
    }
    hfc[tid] = (tid < 200) ? h * fc2w[tid] : 0.f;
    __syncthreads();
    for (int st = 128; st > 0; st >>= 1) { if (tid < st) hfc[tid] += hfc[tid + st]; __syncthreads(); }
    if (tid == 0) out[s] = 1.f / (1.f + expf(-(hfc[0] + fc2b[0])));
}

extern "C" void kernel_launch(void* const* d_in, const int* in_sizes, int n_in,
                              void* d_out, int out_size, void* d_ws, size_t ws_size,
                              hipStream_t stream) {
    const int*   xi   = (const int*)d_in[0];
    const float* emb  = (const float*)d_in[1];
    const float* w3a  = (const float*)d_in[2];
    const float* g3a  = (const float*)d_in[3];
    const float* b3a  = (const float*)d_in[4];
    const float* w3b  = (const float*)d_in[5];
    const float* g3b  = (const float*)d_in[6];
    const float* b3b  = (const float*)d_in[7];
    const float* w3c  = (const float*)d_in[8];
    const float* g3c  = (const float*)d_in[9];
    const float* b3c  = (const float*)d_in[10];
    const float* w3d  = (const float*)d_in[11];
    const float* g3d  = (const float*)d_in[12];
    const float* b3d  = (const float*)d_in[13];
    const float* w2   = (const float*)d_in[14];
    const float* g2   = (const float*)d_in[15];
    const float* b2   = (const float*)d_in[16];
    const float* fc1w = (const float*)d_in[17];
    const float* fc1b = (const float*)d_in[18];
    const float* fc2w = (const float*)d_in[19];
    const float* fc2b = (const float*)d_in[20];
    float* ws = (float*)d_ws;
    float* out = (float*)d_out;
    if (ws_size < WS_FLOATS * sizeof(float)) return;

    float* img = ws + OFF_IMG;
    float* F1  = ws + OFF_F1;   float* E2  = ws + OFF_E2;  float* E1  = ws + OFF_E1;
    float* SS1 = ws + OFF_SS1;  float* par = ws + OFF_PAR;
    float* F2  = ws + OFF_F2;   float* C2b = ws + OFF_C2;  float* T2  = ws + OFF_T2;
    float* SS2F= ws + OFF_SS2F; float* SS2T= ws + OFF_SS2T; float* SS2C= ws + OFF_SS2C;
    float* F3  = ws + OFF_F3;   float* C3b = ws + OFF_C3;  float* T3  = ws + OFF_T3;
    float* SS3F= ws + OFF_SS3F; float* SS3T= ws + OFF_SS3T; float* SS3C= ws + OFF_SS3C;
    float* F4  = ws + OFF_F4;   float* C4b = ws + OFF_C4;  float* T4  = ws + OFF_T4;
    float* SS4F= ws + OFF_SS4F; float* SS4T= ws + OFF_SS4T; float* SS4C= ws + OFF_SS4C;
    float* z   = ws + OFF_Z;    float* cb  = ws + OFF_CB;  float* p2d = ws + OFF_P2D;

    k_embed<<<(B * L * SP + 255) / 256, 256, 0, stream>>>(xi, emb, img);
    k_layer1<<<B * C1 * D1, 256, 0, stream>>>(img, w3a, F1, E2, E1, SS1);
    k_stats1<<<4, 256, 0, stream>>>(SS1, g3a, b3a, par);
    k_apply1<<<(2160000 + 255) / 256, 256, 0, stream>>>(F1, par);
    k_F2<<<B * C2N * D2, 256, 0, stream>>>(F1, w3b, F2, SS2F);
    k_C2<<<1, 256, 0, stream>>>(par, w3b, C2b, SS2C);
    k_T2<<<B * L, 256, 0, stream>>>(F1, E2, E1, par, w3b, T2, SS2T);
    k_stats2<<<8, 256, 0, stream>>>(SS2F, SS2T, SS2C, g3b, b3b, par);
    k_apply2<<<(3601800 + 255) / 256, 256, 0, stream>>>(F2, par);
    k_F3<<<B * C3N * D3, 256, 0, stream>>>(F2, w3c, F3, SS3F);
    k_C3<<<1, 256, 0, stream>>>(C2b, w3c, C3b, SS3C);
    k_T3<<<B * L, 256, 0, stream>>>(F2, T2, C2b, w3c, T3, SS3T);
    k_stats3<<<4, 256, 0, stream>>>(SS3F, SS3T, SS3C, g3c, b3c, par);
    k_apply3<<<(1620900 + 255) / 256, 256, 0, stream>>>(F3, par);
    k_F4<<<B * D4, 256, 0, stream>>>(F3, w3d, F4, SS4F);
    k_C4<<<1, 256, 0, stream>>>(C3b, w3d, C4b, SS4C);
    k_T4<<<B * L, 256, 0, stream>>>(F3, T3, C3b, w3d, T4, SS4T);
    k_stats4<<<1, 256, 0, stream>>>(SS4F, SS4T, SS4C, g3d, b3d, par);
    k_apply4<<<(382725 + 255) / 256, 256, 0, stream>>>(F4, par);
    k_buildz<<<B * L, 256, 0, stream>>>(F4, T4, C4b, z);
    for (int it = 0; it < 5; it++) {
        k_conv2d<<<B * L, 256, 0, stream>>>(z, w2 + (size_t)it * 5625, cb, p2d);
        k_stats2d<<<25, 256, 0, stream>>>(p2d, g2 + it * 25, b2 + it * 25, par);
        k_apply2d<<<(4500000 + 255) / 256, 256, 0, stream>>>(z, cb, par);
    }
    k_head<<<B * L, 256, 0, stream>>>(z, img, fc1w, fc1b, fc2w, fc2b, out);
}